// Round 4
// baseline (171.882 us; speedup 1.0000x reference)
//
#include <hip/hip_runtime.h>

// GCNEncoder: h1 = x@W1; hag = relu(A_norm h1 + b1); h2 = hag@W2; out = A_norm h2 + b2
// A_norm (self loops): out[v] = dinv[v]^2 h[v] + sum_{e:dst=v} dinv[src]dinv[v] h[src]
// Established: float inputs f32 (probed), edges int64 (probed), output f32.
// h1/hag/h2 bf16. GEMMs = MFMA 16x16x32 (128-K-chunk swizzled LDS, unchanged).
// R18: (1) group-per-node aggregation: agg1 = 16-lane group/node (4 nodes/wave),
// agg2 = 8-lane group/node (8 nodes/wave); 4-deep in-group unroll keeps 4
// gathers in flight; NO cross-lane reduce (lane owns its 8 channels); 4x/8x
// fewer waves. (2) fixed-cell sort: stage slot (bucket*nsb+sb)*64+c, cellcnt[]
// per block -> no global atomics, no gcur pre-zero -> prep_w folded into
// stageX. Launch overhead measured ~2.5us/dispatch (R17). 6 dispatches.

#define GCN_IN 256
#define GCN_HID 128
#define GCN_OUT 64

#define BKT 128          // nodes per bucket (dst >> 7)
#define SBE 4096         // edges per superblock
#define CELL 64          // slots per (bucket, superblock) cell; mean 17.4, 11 sigma
#define SRCM 0x1FFFFFFu  // 25-bit src mask

typedef unsigned short ushort_t;
typedef __attribute__((ext_vector_type(8))) short short8;     // 8 bf16 (4 VGPR)
typedef __attribute__((ext_vector_type(8))) unsigned short ushort8;
typedef __attribute__((ext_vector_type(4))) float f32x4;

__device__ inline float bf2f(ushort_t u) {
  union { unsigned int i; float f; } x; x.i = ((unsigned int)u) << 16; return x.f;
}
__device__ inline ushort_t f2bf(float f) {
  union { float f; unsigned int i; } u; u.f = f;
  unsigned int r = u.i + 0x7FFFu + ((u.i >> 16) & 1u);  // RNE
  return (ushort_t)(r >> 16);
}

// ---- stageX: edges -> fixed cells (no global atomics) + W prep + flags ----
// Block sb: LDS cursors seeded to (b*nsb+sb)*CELL; stream ei once; write
// cellcnt[b*nsb+sb]. W transpose+bf16 strided across blocks; block 0 flags.
__global__ __launch_bounds__(256)
void stageX_kernel(const int* __restrict__ ei, int E,
                   const void* __restrict__ W1, const void* __restrict__ W2,
                   ushort_t* __restrict__ Wt1, ushort_t* __restrict__ Wt2,
                   int* __restrict__ flags, int nsb, int nbin,
                   unsigned int* __restrict__ stage, int* __restrict__ cellcnt) {
  __shared__ int cur[256];
  __shared__ int nzc, csh;
  const int t = threadIdx.x;
  const int sb = blockIdx.x;
  if (t == 0) { nzc = 0; csh = 0; }
  __syncthreads();
  if (t < 128) {
    if (ei[2 * t + 1] != 0) atomicAdd(&nzc, 1);     // i64 high words all zero
    ushort_t u = ((const ushort_t*)W1)[2 * t];
    int e = (u >> 7) & 0xFF;
    if (e >= 100 && e <= 140) atomicAdd(&csh, 1);   // bf16-looking exponents
  }
  for (int b = t; b < nbin; b += 256) cur[b] = (b * nsb + sb) * CELL;
  __syncthreads();
  const bool i64 = (nzc == 0);
  const bool f32 = (csh < 64);
  if (sb == 0 && t == 0) flags[0] = f32 ? 1 : 0;    // read by later dispatches

  // W prep (40960 elems over 147 blocks)
  for (int i = sb * 256 + t; i < GCN_IN * GCN_HID + GCN_HID * GCN_OUT;
       i += gridDim.x * 256) {
    if (i < GCN_IN * GCN_HID) {                     // W1[k][n] -> Wt1[n][k]
      int k = i >> 7, nn = i & 127;
      float vv = f32 ? ((const float*)W1)[i] : bf2f(((const ushort_t*)W1)[i]);
      Wt1[nn * GCN_IN + k] = f2bf(vv);
    } else {                                        // W2[k][n] -> Wt2[n][k]
      int j = i - GCN_IN * GCN_HID;
      int k = j >> 6, nn = j & 63;
      float vv = f32 ? ((const float*)W2)[j] : bf2f(((const ushort_t*)W2)[j]);
      Wt2[nn * GCN_HID + k] = f2bf(vv);
    }
  }

  const int base = sb * SBE;
  int end = base + SBE; if (end > E) end = E;
  for (int i = base + t; i < end; i += 256) {
    int s, d;
    if (i64) { s = ei[2 * i]; d = ei[2 * E + 2 * i]; }
    else     { s = ei[i];     d = ei[E + i]; }
    int b = d >> 7;
    int pos = atomicAdd(&cur[b], 1);                // LDS atomic cursor
    if (pos - (b * nsb + sb) * CELL < CELL)         // clamp (astronomical)
      stage[pos] = (unsigned int)s | ((unsigned int)(d & 127) << 25);
  }
  __syncthreads();
  for (int b = t; b < nbin; b += 256) {
    int c = cur[b] - (b * nsb + sb) * CELL;
    cellcnt[b * nsb + sb] = (c > CELL) ? CELL : c;
  }
}

// ---- scatter: block per bucket. Flattened coalesced cell iteration; local
// hist -> scan -> row_ptr/deg/dinv -> dst_local-sorted csr_src.
// Bucket csr window = b*nsb*CELL (padded; no overflow possible).
__global__ __launch_bounds__(256)
void scatter_kernel(const unsigned int* __restrict__ stage,
                    const int* __restrict__ cellcnt, int nsb, int nbin,
                    int* __restrict__ csr_src,
                    int* __restrict__ row_ptr, int* __restrict__ deg,
                    float* __restrict__ dinv, int n) {
  __shared__ int ccnt[256];
  __shared__ int lcnt[BKT];
  __shared__ int lscan[BKT];
  __shared__ int lcur[BKT];
  const int t = threadIdx.x;                // 256 threads
  const int b = blockIdx.x;
  const int node0 = b * BKT;
  const int nn = (n - node0 < BKT) ? (n - node0) : BKT;
  if (t < nsb) ccnt[t] = cellcnt[b * nsb + t];
  if (t < BKT) lcnt[t] = 0;
  __syncthreads();
  const unsigned int* srow = stage + (size_t)b * nsb * CELL;
  const int tot = nsb * CELL;
  for (int idx = t; idx < tot; idx += 256) {
    if ((idx & (CELL - 1)) < ccnt[idx >> 6])
      atomicAdd(&lcnt[srow[idx] >> 25], 1); // LDS atomic, 128 counters
  }
  __syncthreads();
  if (t < BKT) lscan[t] = lcnt[t];
  __syncthreads();
  for (int off = 1; off < BKT; off <<= 1) {  // Hillis-Steele inclusive scan
    int v = 0;
    if (t < BKT && t >= off) v = lscan[t - off];
    __syncthreads();
    if (t < BKT) lscan[t] += v;
    __syncthreads();
  }
  const int rb = b * nsb * CELL;
  if (t < BKT) {
    int excl = rb + lscan[t] - lcnt[t];
    lcur[t] = excl;
    if (t < nn) {
      row_ptr[node0 + t] = excl;
      deg[node0 + t] = lcnt[t];
      dinv[node0 + t] = rsqrtf((float)(lcnt[t] + 1));  // +1 self loop
    }
  }
  __syncthreads();
  for (int idx = t; idx < tot; idx += 256) {
    if ((idx & (CELL - 1)) < ccnt[idx >> 6]) {
      unsigned int p = srow[idx];
      int l = p >> 25;
      int pos = atomicAdd(&lcur[l], 1);     // LDS atomic cursor
      csr_src[pos] = (int)(p & SRCM);
    }
  }
}

// ---------------- MFMA GEMM: C[M,NC] = A[M,K] @ Bt[NC,K]^T, bf16 in/out --------
// Full 128-K-chunk staged in LDS (A 8KB + B up to 32KB), XOR-swizzle
// byte ^= (row&7)<<4 kills the stride-256B bank conflict.
template<int K, int NC, int A_MODE>
__global__ __launch_bounds__(256)
void gemm_mfma_kernel(const void* __restrict__ A, const ushort_t* __restrict__ Bt,
                      ushort_t* __restrict__ C, int M, const int* __restrict__ flags) {
  constexpr int KH = (K > 128) ? 128 : K;     // K-chunk staged at once
  constexpr int KPC = KH / 8;                 // 16B chunks per row
  constexpr int NT = NC / 32;
  __shared__ ushort_t As[32 * KH];
  __shared__ ushort_t Bs[NC * KH];
  const int tid = threadIdx.x;
  const int wv = tid >> 6;
  const int lane = tid & 63;
  const int ml = lane & 15;
  const int quad = lane >> 4;
  const int row0 = blockIdx.x * 32;
  const int mrow = (wv & 1) * 16 + ml;
  const int ncol0 = (wv >> 1) * (NC / 2);
  const bool aF32 = (A_MODE == 0) && (flags[0] != 0);
  f32x4 acc[NT] = {};

  for (int ch = 0; ch < K; ch += KH) {
    if (ch) __syncthreads();                  // all waves done with prev chunk
    // stage A chunk: 32 rows x KH bf16, swizzled
    for (int c = tid; c < 32 * KPC; c += 256) {
      int r = c / KPC, cq = c % KPC;
      ushort8 o;
      if (row0 + r < M) {
        if (aF32) {
          const float* ap = (const float*)A + (size_t)(row0 + r) * K + ch + cq * 8;
          float4 f0 = *(const float4*)ap;
          float4 f1 = *(const float4*)(ap + 4);
          o[0] = f2bf(f0.x); o[1] = f2bf(f0.y); o[2] = f2bf(f0.z); o[3] = f2bf(f0.w);
          o[4] = f2bf(f1.x); o[5] = f2bf(f1.y); o[6] = f2bf(f1.z); o[7] = f2bf(f1.w);
        } else {
          o = *(const ushort8*)((const ushort_t*)A + (size_t)(row0 + r) * K + ch + cq * 8);
        }
      } else {
        o = (ushort8)0;
      }
      int byte = (cq * 16) ^ ((r & 7) << 4);
      *(ushort8*)((char*)As + r * (KH * 2) + byte) = o;
    }
    // stage B chunk: NC rows x KH bf16, swizzled
    for (int c = tid; c < NC * KPC; c += 256) {
      int nr = c / KPC, cq = c % KPC;
      ushort8 o = *(const ushort8*)(Bt + (size_t)nr * K + ch + cq * 8);
      int byte = (cq * 16) ^ ((nr & 7) << 4);
      *(ushort8*)((char*)Bs + nr * (KH * 2) + byte) = o;
    }
    __syncthreads();
#pragma unroll
    for (int kt = 0; kt < KH; kt += 32) {
      int abyte = (kt * 2 + quad * 16) ^ ((mrow & 7) << 4);
      short8 af = *(const short8*)((const char*)As + mrow * (KH * 2) + abyte);
#pragma unroll
      for (int t = 0; t < NT; ++t) {
        int nr = ncol0 + t * 16 + ml;
        int bbyte = (kt * 2 + quad * 16) ^ ((nr & 7) << 4);
        short8 bf = *(const short8*)((const char*)Bs + nr * (KH * 2) + bbyte);
        acc[t] = __builtin_amdgcn_mfma_f32_16x16x32_bf16(af, bf, acc[t], 0, 0, 0);
      }
    }
  }

  const int orow = row0 + (wv & 1) * 16 + quad * 4;
#pragma unroll
  for (int t = 0; t < NT; ++t) {
    int col = ncol0 + t * 16 + ml;
#pragma unroll
    for (int r = 0; r < 4; ++r) {
      if (orow + r < M)
        C[(size_t)(orow + r) * NC + col] = f2bf(acc[t][r]);
    }
  }
}

// ---------------- aggregation: 16-lane group per node ----------------
// agg1: group = 16 lanes = 1 node (4 nodes/wave). Lane q owns channels
// q*8..q*8+7. Per 16-edge strip: lane q loads csr/dinv for edge q (oob lanes
// carry sv=0,dv=0 -> zero-weight gather of h[0]); j-unroll 4 keeps 4
// independent 256B row-gathers in flight. shfl sources stay inside the group
// (uniform control flow within group -> divergence-safe). No cross-lane
// reduce: each lane's acc is final.
__global__ void aggregate_relu_kernel(const ushort_t* __restrict__ h,
                                      const int* __restrict__ row_ptr,
                                      const int* __restrict__ deg,
                                      const int* __restrict__ csr_src,
                                      const float* __restrict__ dinv,
                                      const void* __restrict__ bias,
                                      ushort_t* __restrict__ outp, int n,
                                      const int* __restrict__ flags) {
  const int lane = threadIdx.x & 63;
  const int v = blockIdx.x * 16 + (threadIdx.x >> 4);  // 16 nodes per block
  if (v >= n) return;
  const int q = lane & 15;
  const int gb = lane & 48;                            // group base in wave
  float acc[8] = {};
  const int beg = row_ptr[v];
  const int end = beg + deg[v];
  for (int base = beg; base < end; base += 16) {
    int navail = end - base; if (navail > 16) navail = 16;
    int sv = 0; float dv = 0.f;
    if (base + q < end) { sv = csr_src[base + q]; dv = dinv[sv]; }
    for (int j = 0; j < navail; j += 4) {
      int s0 = __shfl(sv, gb + j + 0), s1 = __shfl(sv, gb + j + 1);
      int s2 = __shfl(sv, gb + j + 2), s3 = __shfl(sv, gb + j + 3);
      float d0 = __shfl(dv, gb + j + 0), d1 = __shfl(dv, gb + j + 1);
      float d2 = __shfl(dv, gb + j + 2), d3 = __shfl(dv, gb + j + 3);
      ushort8 hv0 = *(const ushort8*)(h + (size_t)s0 * GCN_HID + q * 8);
      ushort8 hv1 = *(const ushort8*)(h + (size_t)s1 * GCN_HID + q * 8);
      ushort8 hv2 = *(const ushort8*)(h + (size_t)s2 * GCN_HID + q * 8);
      ushort8 hv3 = *(const ushort8*)(h + (size_t)s3 * GCN_HID + q * 8);
#pragma unroll
      for (int k = 0; k < 8; ++k) {
        acc[k] = fmaf(d0, bf2f(hv0[k]), acc[k]);
        acc[k] = fmaf(d1, bf2f(hv1[k]), acc[k]);
        acc[k] = fmaf(d2, bf2f(hv2[k]), acc[k]);
        acc[k] = fmaf(d3, bf2f(hv3[k]), acc[k]);
      }
    }
  }
  float di = dinv[v];
  float sl = di * di;
  ushort8 hv = *(const ushort8*)(h + (size_t)v * GCN_HID + q * 8);
  const bool bF32 = flags[0] != 0;
  ushort8 o;
#pragma unroll
  for (int k = 0; k < 8; ++k) {
    float bv = bF32 ? ((const float*)bias)[q * 8 + k]
                    : bf2f(((const ushort_t*)bias)[q * 8 + k]);
    o[k] = f2bf(fmaxf(di * acc[k] + sl * bf2f(hv[k]) + bv, 0.f));
  }
  *(ushort8*)(outp + (size_t)v * GCN_HID + q * 8) = o;
}

// agg2: group = 8 lanes = 1 node (8 nodes/wave), 128B rows, same scheme.
__global__ void aggregate_out_kernel(const ushort_t* __restrict__ h,
                                     const int* __restrict__ row_ptr,
                                     const int* __restrict__ deg,
                                     const int* __restrict__ csr_src,
                                     const float* __restrict__ dinv,
                                     const void* __restrict__ bias,
                                     void* __restrict__ outp, int n,
                                     const int* __restrict__ flags) {
  const int lane = threadIdx.x & 63;
  const int v = blockIdx.x * 32 + (threadIdx.x >> 3);  // 32 nodes per block
  if (v >= n) return;
  const int q = lane & 7;
  const int gb = lane & 56;                            // group base in wave
  float acc[8] = {};
  const int beg = row_ptr[v];
  const int end = beg + deg[v];
  for (int base = beg; base < end; base += 8) {
    int navail = end - base; if (navail > 8) navail = 8;
    int sv = 0; float dv = 0.f;
    if (base + q < end) { sv = csr_src[base + q]; dv = dinv[sv]; }
    for (int j = 0; j < navail; j += 4) {
      int s0 = __shfl(sv, gb + j + 0), s1 = __shfl(sv, gb + j + 1);
      int s2 = __shfl(sv, gb + j + 2), s3 = __shfl(sv, gb + j + 3);
      float d0 = __shfl(dv, gb + j + 0), d1 = __shfl(dv, gb + j + 1);
      float d2 = __shfl(dv, gb + j + 2), d3 = __shfl(dv, gb + j + 3);
      ushort8 hv0 = *(const ushort8*)(h + (size_t)s0 * GCN_OUT + q * 8);
      ushort8 hv1 = *(const ushort8*)(h + (size_t)s1 * GCN_OUT + q * 8);
      ushort8 hv2 = *(const ushort8*)(h + (size_t)s2 * GCN_OUT + q * 8);
      ushort8 hv3 = *(const ushort8*)(h + (size_t)s3 * GCN_OUT + q * 8);
#pragma unroll
      for (int k = 0; k < 8; ++k) {
        acc[k] = fmaf(d0, bf2f(hv0[k]), acc[k]);
        acc[k] = fmaf(d1, bf2f(hv1[k]), acc[k]);
        acc[k] = fmaf(d2, bf2f(hv2[k]), acc[k]);
        acc[k] = fmaf(d3, bf2f(hv3[k]), acc[k]);
      }
    }
  }
  float di = dinv[v];
  float sl = di * di;
  ushort8 hv = *(const ushort8*)(h + (size_t)v * GCN_OUT + q * 8);
  const bool oF32 = flags[0] != 0;
  float r[8];
#pragma unroll
  for (int k = 0; k < 8; ++k) {
    float bv = oF32 ? ((const float*)bias)[q * 8 + k]
                    : bf2f(((const ushort_t*)bias)[q * 8 + k]);
    r[k] = di * acc[k] + sl * bf2f(hv[k]) + bv;
  }
  if (oF32) {
    float* op = (float*)outp + (size_t)v * GCN_OUT + q * 8;
    *(float4*)op = make_float4(r[0], r[1], r[2], r[3]);
    *(float4*)(op + 4) = make_float4(r[4], r[5], r[6], r[7]);
  } else {
    ushort8 o;
#pragma unroll
    for (int k = 0; k < 8; ++k) o[k] = f2bf(r[k]);
    *(ushort8*)((ushort_t*)outp + (size_t)v * GCN_OUT + q * 8) = o;
  }
}

// ---------------- launch ----------------

extern "C" void kernel_launch(void* const* d_in, const int* in_sizes, int n_in,
                              void* d_out, int out_size, void* d_ws, size_t ws_size,
                              hipStream_t stream) {
  const void* x  = d_in[0];               // [N, 256] f32 (probed)
  const int*  ei = (const int*)d_in[1];   // [2, E] int32/int64 (probed)
  const void* W1 = d_in[2];               // [256,128]
  const void* b1 = d_in[3];               // [128]
  const void* W2 = d_in[4];               // [128,64]
  const void* b2 = d_in[5];               // [64]

  const int N = in_sizes[0] / GCN_IN;     // 30000
  const int E = in_sizes[1] / 2;          // 600000
  const int nsb  = (E + SBE - 1) / SBE;   // 147 superblocks
  const int nbin = (N + BKT - 1) / BKT;   // 235 buckets (<=256)

  size_t off = 0;
  auto alloc = [&](size_t bytes) -> void* {
    void* p = (char*)d_ws + off;
    off += (bytes + 255) & ~(size_t)255;
    return p;
  };
  int*          flags   = (int*)alloc(256);
  unsigned int* stage   = (unsigned int*)alloc((size_t)nbin * nsb * CELL * 4);
  int*          cellcnt = (int*)alloc((size_t)nbin * nsb * 4);
  int*          csr_src = (int*)alloc((size_t)nbin * nsb * CELL * 4);
  int*          row_ptr = (int*)alloc((size_t)N * 4);
  int*          deg     = (int*)alloc((size_t)N * 4);
  float*        dinv    = (float*)alloc((size_t)N * 4);
  ushort_t*     h1      = (ushort_t*)alloc((size_t)N * GCN_HID * 2);  // bf16
  ushort_t*     hag     = (ushort_t*)alloc((size_t)N * GCN_HID * 2);  // bf16
  ushort_t*     wt1     = (ushort_t*)alloc((size_t)GCN_HID * GCN_IN * 2);
  ushort_t*     wt2     = (ushort_t*)alloc((size_t)GCN_OUT * GCN_HID * 2);
  ushort_t*     h2      = h1;  // h1 dead after hag; reuse for GEMM2 output

  stageX_kernel<<<nsb, 256, 0, stream>>>(ei, E, W1, W2, wt1, wt2, flags,
                                         nsb, nbin, stage, cellcnt);
  scatter_kernel<<<nbin, 256, 0, stream>>>(stage, cellcnt, nsb, nbin, csr_src,
                                           row_ptr, deg, dinv, N);

  // GEMM1: [N,256] @ [256,128] -> h1 bf16 (MFMA)
  gemm_mfma_kernel<GCN_IN, GCN_HID, 0>
      <<<(N + 31) / 32, 256, 0, stream>>>(x, wt1, h1, N, flags);

  aggregate_relu_kernel<<<(N + 15) / 16, 256, 0, stream>>>(
      h1, row_ptr, deg, csr_src, dinv, b1, hag, N, flags);

  // GEMM2: [N,128] @ [128,64] -> h2 bf16 (MFMA, A bf16)
  gemm_mfma_kernel<GCN_HID, GCN_OUT, 2>
      <<<(N + 31) / 32, 256, 0, stream>>>(hag, wt2, h2, N, flags);

  aggregate_out_kernel<<<(N + 31) / 32, 256, 0, stream>>>(
      h2, row_ptr, deg, csr_src, dinv, b2, d_out, N, flags);
}

// Round 5
// 158.531 us; speedup vs baseline: 1.0842x; 1.0842x over previous
//
#include <hip/hip_runtime.h>

// GCNEncoder: h1 = x@W1; hag = relu(A_norm h1 + b1); h2 = hag@W2; out = A_norm h2 + b2
// A_norm (self loops): out[v] = dinv[v]^2 h[v] + sum_{e:dst=v} dinv[src]dinv[v] h[src]
// Established: float inputs f32 (probed), edges int64 (probed), output f32.
// h1/hag/h2 bf16. GEMMs = MFMA 16x16x32 (128-K-chunk swizzled LDS).
// R19: attribution round. R18 (+11us) bundled fixed-cell sort + group-per-node
// agg. Theory: regressor = fixed-cell SCATTER (235 blocks = 1/CU, latency-bound;
// padded-slot loop 37 iters @ 27% density vs 10 useful). REVERT sort to R17's
// proven gcur-reservation + CAP windows (160.8us); KEEP R18 group-per-node agg
// (per-edge inst counts identical to wave-per-node; waste slots are L1-hit
// h[0] broadcasts). 7 dispatches.

#define GCN_IN 256
#define GCN_HID 128
#define GCN_OUT 64

#define BKT 128          // nodes per bucket (dst >> 7)
#define SBE 4096         // edges per superblock
#define CAP 4096         // padded slots per bucket (expected 2560, ~30 sigma)
#define SRCM 0x1FFFFFFu  // 25-bit src mask

typedef unsigned short ushort_t;
typedef __attribute__((ext_vector_type(8))) short short8;     // 8 bf16 (4 VGPR)
typedef __attribute__((ext_vector_type(8))) unsigned short ushort8;
typedef __attribute__((ext_vector_type(4))) float f32x4;

__device__ inline float bf2f(ushort_t u) {
  union { unsigned int i; float f; } x; x.i = ((unsigned int)u) << 16; return x.f;
}
__device__ inline ushort_t f2bf(float f) {
  union { float f; unsigned int i; } u; u.f = f;
  unsigned int r = u.i + 0x7FFFu + ((u.i >> 16) & 1u);  // RNE
  return (ushort_t)(r >> 16);
}

// ---- stageX: fused hist + reserve + bucket-scatter (per superblock) ----
// Per block: cache 16 edges/thread in registers (compile-time indices), LDS
// hist over 235 buckets, ONE global atomicAdd per non-empty bucket to reserve
// a window in the padded stage array, then LDS-cursor scatter.
// Packed u32: src (25b) | dst_local (7b) << 25.
__global__ __launch_bounds__(256)
void stageX_kernel(const int* __restrict__ ei, int E,
                   int* __restrict__ gcur, int nbin,
                   unsigned int* __restrict__ stage) {
  __shared__ int lcnt[256];
  __shared__ int cur[256];
  __shared__ int nzc;
  const int t = threadIdx.x;
  const int sb = blockIdx.x;
  lcnt[t] = 0;
  if (t == 0) nzc = 0;
  __syncthreads();
  if (t < 128 && ei[2 * t + 1] != 0) atomicAdd(&nzc, 1);
  __syncthreads();
  const bool i64 = (nzc == 0);
  const int base = sb * SBE;
  int end = base + SBE; if (end > E) end = E;

  unsigned int p[16];
  int bk[16];
#pragma unroll
  for (int k = 0; k < 16; ++k) {
    int i = base + t + k * 256;
    bk[k] = -1;
    if (i < end) {
      int s, d;
      if (i64) { s = ei[2 * i]; d = ei[2 * E + 2 * i]; }
      else     { s = ei[i];     d = ei[E + i]; }
      p[k] = (unsigned int)s | ((unsigned int)(d & 127) << 25);
      bk[k] = d >> 7;
      atomicAdd(&lcnt[bk[k]], 1);             // LDS atomic
    }
  }
  __syncthreads();
  for (int b = t; b < nbin; b += 256) {
    int c = lcnt[b];
    cur[b] = b * CAP + (c ? atomicAdd(&gcur[b], c) : 0);  // global reservation
  }
  __syncthreads();
#pragma unroll
  for (int k = 0; k < 16; ++k) {
    if (bk[k] >= 0) {
      int pos = atomicAdd(&cur[bk[k]], 1);    // LDS atomic cursor
      if (pos < (bk[k] + 1) * CAP)            // overflow guard (never expected)
        stage[pos] = p[k];
    }
  }
}

// ---- scatter: block per bucket. Local hist -> local scan -> row_ptr/deg/dinv
// -> dst_local-sorted csr_src within the bucket's padded window.
__global__ __launch_bounds__(256)
void scatter_kernel(const unsigned int* __restrict__ stage,
                    const int* __restrict__ gcur, int nbin,
                    int* __restrict__ csr_src,
                    int* __restrict__ row_ptr, int* __restrict__ deg,
                    float* __restrict__ dinv, int n) {
  __shared__ int lcnt[BKT];
  __shared__ int lscan[BKT];
  __shared__ int lcur[BKT];
  const int t = threadIdx.x;                // 256 threads
  const int b = blockIdx.x;
  const int node0 = b * BKT;
  const int nn = (n - node0 < BKT) ? (n - node0) : BKT;
  const int rb = b * CAP;
  const int re = rb + gcur[b];
  if (t < BKT) lcnt[t] = 0;
  __syncthreads();
  for (int i = rb + t; i < re; i += 256)
    atomicAdd(&lcnt[stage[i] >> 25], 1);    // LDS atomic, 128 counters
  __syncthreads();
  if (t < BKT) lscan[t] = lcnt[t];
  __syncthreads();
  for (int off = 1; off < BKT; off <<= 1) {  // Hillis-Steele inclusive scan
    int v = 0;
    if (t < BKT && t >= off) v = lscan[t - off];
    __syncthreads();
    if (t < BKT) lscan[t] += v;
    __syncthreads();
  }
  if (t < BKT) {
    int excl = rb + lscan[t] - lcnt[t];
    lcur[t] = excl;
    if (t < nn) {
      row_ptr[node0 + t] = excl;
      deg[node0 + t] = lcnt[t];
      dinv[node0 + t] = rsqrtf((float)(lcnt[t] + 1));  // +1 self loop
    }
  }
  __syncthreads();
  for (int i = rb + t; i < re; i += 256) {
    unsigned int p = stage[i];
    int l = p >> 25;
    int pos = atomicAdd(&lcur[l], 1);       // LDS atomic cursor
    csr_src[pos] = (int)(p & SRCM);         // write within ~10KB window
  }
}

// ---------------- weight prep: transpose + bf16 (Wt[n][k]) + flags + gcur=0 ----
// f32 detection local per block from W1 halfword exponent pattern; block 0
// publishes flags[0] and zeroes the global bucket cursors (stream-ordered
// before stageX; re-runs every graph replay).
__global__ void prep_w_kernel(const void* __restrict__ W1, const void* __restrict__ W2,
                              ushort_t* __restrict__ Wt1, ushort_t* __restrict__ Wt2,
                              int* __restrict__ flags, int* __restrict__ gcur) {
  __shared__ int csh;
  if (threadIdx.x == 0) csh = 0;
  __syncthreads();
  if (threadIdx.x < 128) {
    ushort_t u = ((const ushort_t*)W1)[2 * threadIdx.x];
    int e = (u >> 7) & 0xFF;
    if (e >= 100 && e <= 140) atomicAdd(&csh, 1);   // bf16-looking exponents
  }
  __syncthreads();
  bool f32 = (csh < 64);
  if (blockIdx.x == 0) {
    if (threadIdx.x == 0) flags[0] = f32 ? 1 : 0;
    gcur[threadIdx.x] = 0;                  // 256 >= nbin cursors
  }

  int i = blockIdx.x * blockDim.x + threadIdx.x;
  if (i < GCN_IN * GCN_HID) {                 // W1[k][n]
    int k = i >> 7, n = i & 127;
    float v = f32 ? ((const float*)W1)[i] : bf2f(((const ushort_t*)W1)[i]);
    Wt1[n * GCN_IN + k] = f2bf(v);
  }
  int j = i - GCN_IN * GCN_HID;
  if (j >= 0 && j < GCN_HID * GCN_OUT) {      // W2[k][n]
    int k = j >> 6, n = j & 63;
    float v = f32 ? ((const float*)W2)[j] : bf2f(((const ushort_t*)W2)[j]);
    Wt2[n * GCN_HID + k] = f2bf(v);
  }
}

// ---------------- MFMA GEMM: C[M,NC] = A[M,K] @ Bt[NC,K]^T, bf16 in/out --------
// Full 128-K-chunk staged in LDS (A 8KB + B up to 32KB), XOR-swizzle
// byte ^= (row&7)<<4 kills the stride-256B bank conflict.
template<int K, int NC, int A_MODE>
__global__ __launch_bounds__(256)
void gemm_mfma_kernel(const void* __restrict__ A, const ushort_t* __restrict__ Bt,
                      ushort_t* __restrict__ C, int M, const int* __restrict__ flags) {
  constexpr int KH = (K > 128) ? 128 : K;     // K-chunk staged at once
  constexpr int KPC = KH / 8;                 // 16B chunks per row
  constexpr int NT = NC / 32;
  __shared__ ushort_t As[32 * KH];
  __shared__ ushort_t Bs[NC * KH];
  const int tid = threadIdx.x;
  const int wv = tid >> 6;
  const int lane = tid & 63;
  const int ml = lane & 15;
  const int quad = lane >> 4;
  const int row0 = blockIdx.x * 32;
  const int mrow = (wv & 1) * 16 + ml;
  const int ncol0 = (wv >> 1) * (NC / 2);
  const bool aF32 = (A_MODE == 0) && (flags[0] != 0);
  f32x4 acc[NT] = {};

  for (int ch = 0; ch < K; ch += KH) {
    if (ch) __syncthreads();                  // all waves done with prev chunk
    // stage A chunk: 32 rows x KH bf16, swizzled
    for (int c = tid; c < 32 * KPC; c += 256) {
      int r = c / KPC, cq = c % KPC;
      ushort8 o;
      if (row0 + r < M) {
        if (aF32) {
          const float* ap = (const float*)A + (size_t)(row0 + r) * K + ch + cq * 8;
          float4 f0 = *(const float4*)ap;
          float4 f1 = *(const float4*)(ap + 4);
          o[0] = f2bf(f0.x); o[1] = f2bf(f0.y); o[2] = f2bf(f0.z); o[3] = f2bf(f0.w);
          o[4] = f2bf(f1.x); o[5] = f2bf(f1.y); o[6] = f2bf(f1.z); o[7] = f2bf(f1.w);
        } else {
          o = *(const ushort8*)((const ushort_t*)A + (size_t)(row0 + r) * K + ch + cq * 8);
        }
      } else {
        o = (ushort8)0;
      }
      int byte = (cq * 16) ^ ((r & 7) << 4);
      *(ushort8*)((char*)As + r * (KH * 2) + byte) = o;
    }
    // stage B chunk: NC rows x KH bf16, swizzled
    for (int c = tid; c < NC * KPC; c += 256) {
      int nr = c / KPC, cq = c % KPC;
      ushort8 o = *(const ushort8*)(Bt + (size_t)nr * K + ch + cq * 8);
      int byte = (cq * 16) ^ ((nr & 7) << 4);
      *(ushort8*)((char*)Bs + nr * (KH * 2) + byte) = o;
    }
    __syncthreads();
#pragma unroll
    for (int kt = 0; kt < KH; kt += 32) {
      int abyte = (kt * 2 + quad * 16) ^ ((mrow & 7) << 4);
      short8 af = *(const short8*)((const char*)As + mrow * (KH * 2) + abyte);
#pragma unroll
      for (int t = 0; t < NT; ++t) {
        int nr = ncol0 + t * 16 + ml;
        int bbyte = (kt * 2 + quad * 16) ^ ((nr & 7) << 4);
        short8 bf = *(const short8*)((const char*)Bs + nr * (KH * 2) + bbyte);
        acc[t] = __builtin_amdgcn_mfma_f32_16x16x32_bf16(af, bf, acc[t], 0, 0, 0);
      }
    }
  }

  const int orow = row0 + (wv & 1) * 16 + quad * 4;
#pragma unroll
  for (int t = 0; t < NT; ++t) {
    int col = ncol0 + t * 16 + ml;
#pragma unroll
    for (int r = 0; r < 4; ++r) {
      if (orow + r < M)
        C[(size_t)(orow + r) * NC + col] = f2bf(acc[t][r]);
    }
  }
}

// ---------------- aggregation: lane-group per node (R18 kernels) ----------------
// agg1: group = 16 lanes = 1 node (4 nodes/wave). Lane q owns channels
// q*8..q*8+7. Per 16-edge strip: lane q loads csr/dinv for edge q (oob lanes
// carry sv=0,dv=0 -> zero-weight gather of h[0]); j-unroll 4 keeps 4
// independent 256B row-gathers in flight. No cross-lane reduce.
__global__ void aggregate_relu_kernel(const ushort_t* __restrict__ h,
                                      const int* __restrict__ row_ptr,
                                      const int* __restrict__ deg,
                                      const int* __restrict__ csr_src,
                                      const float* __restrict__ dinv,
                                      const void* __restrict__ bias,
                                      ushort_t* __restrict__ outp, int n,
                                      const int* __restrict__ flags) {
  const int lane = threadIdx.x & 63;
  const int v = blockIdx.x * 16 + (threadIdx.x >> 4);  // 16 nodes per block
  if (v >= n) return;
  const int q = lane & 15;
  const int gb = lane & 48;                            // group base in wave
  float acc[8] = {};
  const int beg = row_ptr[v];
  const int end = beg + deg[v];
  for (int base = beg; base < end; base += 16) {
    int navail = end - base; if (navail > 16) navail = 16;
    int sv = 0; float dv = 0.f;
    if (base + q < end) { sv = csr_src[base + q]; dv = dinv[sv]; }
    for (int j = 0; j < navail; j += 4) {
      int s0 = __shfl(sv, gb + j + 0), s1 = __shfl(sv, gb + j + 1);
      int s2 = __shfl(sv, gb + j + 2), s3 = __shfl(sv, gb + j + 3);
      float d0 = __shfl(dv, gb + j + 0), d1 = __shfl(dv, gb + j + 1);
      float d2 = __shfl(dv, gb + j + 2), d3 = __shfl(dv, gb + j + 3);
      ushort8 hv0 = *(const ushort8*)(h + (size_t)s0 * GCN_HID + q * 8);
      ushort8 hv1 = *(const ushort8*)(h + (size_t)s1 * GCN_HID + q * 8);
      ushort8 hv2 = *(const ushort8*)(h + (size_t)s2 * GCN_HID + q * 8);
      ushort8 hv3 = *(const ushort8*)(h + (size_t)s3 * GCN_HID + q * 8);
#pragma unroll
      for (int k = 0; k < 8; ++k) {
        acc[k] = fmaf(d0, bf2f(hv0[k]), acc[k]);
        acc[k] = fmaf(d1, bf2f(hv1[k]), acc[k]);
        acc[k] = fmaf(d2, bf2f(hv2[k]), acc[k]);
        acc[k] = fmaf(d3, bf2f(hv3[k]), acc[k]);
      }
    }
  }
  float di = dinv[v];
  float sl = di * di;
  ushort8 hv = *(const ushort8*)(h + (size_t)v * GCN_HID + q * 8);
  const bool bF32 = flags[0] != 0;
  ushort8 o;
#pragma unroll
  for (int k = 0; k < 8; ++k) {
    float bv = bF32 ? ((const float*)bias)[q * 8 + k]
                    : bf2f(((const ushort_t*)bias)[q * 8 + k]);
    o[k] = f2bf(fmaxf(di * acc[k] + sl * bf2f(hv[k]) + bv, 0.f));
  }
  *(ushort8*)(outp + (size_t)v * GCN_HID + q * 8) = o;
}

// agg2: group = 8 lanes = 1 node (8 nodes/wave), 128B rows, same scheme.
__global__ void aggregate_out_kernel(const ushort_t* __restrict__ h,
                                     const int* __restrict__ row_ptr,
                                     const int* __restrict__ deg,
                                     const int* __restrict__ csr_src,
                                     const float* __restrict__ dinv,
                                     const void* __restrict__ bias,
                                     void* __restrict__ outp, int n,
                                     const int* __restrict__ flags) {
  const int lane = threadIdx.x & 63;
  const int v = blockIdx.x * 32 + (threadIdx.x >> 3);  // 32 nodes per block
  if (v >= n) return;
  const int q = lane & 7;
  const int gb = lane & 56;                            // group base in wave
  float acc[8] = {};
  const int beg = row_ptr[v];
  const int end = beg + deg[v];
  for (int base = beg; base < end; base += 8) {
    int navail = end - base; if (navail > 8) navail = 8;
    int sv = 0; float dv = 0.f;
    if (base + q < end) { sv = csr_src[base + q]; dv = dinv[sv]; }
    for (int j = 0; j < navail; j += 4) {
      int s0 = __shfl(sv, gb + j + 0), s1 = __shfl(sv, gb + j + 1);
      int s2 = __shfl(sv, gb + j + 2), s3 = __shfl(sv, gb + j + 3);
      float d0 = __shfl(dv, gb + j + 0), d1 = __shfl(dv, gb + j + 1);
      float d2 = __shfl(dv, gb + j + 2), d3 = __shfl(dv, gb + j + 3);
      ushort8 hv0 = *(const ushort8*)(h + (size_t)s0 * GCN_OUT + q * 8);
      ushort8 hv1 = *(const ushort8*)(h + (size_t)s1 * GCN_OUT + q * 8);
      ushort8 hv2 = *(const ushort8*)(h + (size_t)s2 * GCN_OUT + q * 8);
      ushort8 hv3 = *(const ushort8*)(h + (size_t)s3 * GCN_OUT + q * 8);
#pragma unroll
      for (int k = 0; k < 8; ++k) {
        acc[k] = fmaf(d0, bf2f(hv0[k]), acc[k]);
        acc[k] = fmaf(d1, bf2f(hv1[k]), acc[k]);
        acc[k] = fmaf(d2, bf2f(hv2[k]), acc[k]);
        acc[k] = fmaf(d3, bf2f(hv3[k]), acc[k]);
      }
    }
  }
  float di = dinv[v];
  float sl = di * di;
  ushort8 hv = *(const ushort8*)(h + (size_t)v * GCN_OUT + q * 8);
  const bool oF32 = flags[0] != 0;
  float r[8];
#pragma unroll
  for (int k = 0; k < 8; ++k) {
    float bv = oF32 ? ((const float*)bias)[q * 8 + k]
                    : bf2f(((const ushort_t*)bias)[q * 8 + k]);
    r[k] = di * acc[k] + sl * bf2f(hv[k]) + bv;
  }
  if (oF32) {
    float* op = (float*)outp + (size_t)v * GCN_OUT + q * 8;
    *(float4*)op = make_float4(r[0], r[1], r[2], r[3]);
    *(float4*)(op + 4) = make_float4(r[4], r[5], r[6], r[7]);
  } else {
    ushort8 o;
#pragma unroll
    for (int k = 0; k < 8; ++k) o[k] = f2bf(r[k]);
    *(ushort8*)((ushort_t*)outp + (size_t)v * GCN_OUT + q * 8) = o;
  }
}

// ---------------- launch ----------------

extern "C" void kernel_launch(void* const* d_in, const int* in_sizes, int n_in,
                              void* d_out, int out_size, void* d_ws, size_t ws_size,
                              hipStream_t stream) {
  const void* x  = d_in[0];               // [N, 256] f32 (probed)
  const int*  ei = (const int*)d_in[1];   // [2, E] int32/int64 (probed)
  const void* W1 = d_in[2];               // [256,128]
  const void* b1 = d_in[3];               // [128]
  const void* W2 = d_in[4];               // [128,64]
  const void* b2 = d_in[5];               // [64]

  const int N = in_sizes[0] / GCN_IN;     // 30000
  const int E = in_sizes[1] / 2;          // 600000
  const int nsb  = (E + SBE - 1) / SBE;   // 147 superblocks
  const int nbin = (N + BKT - 1) / BKT;   // 235 buckets (<=256)

  size_t off = 0;
  auto alloc = [&](size_t bytes) -> void* {
    void* p = (char*)d_ws + off;
    off += (bytes + 255) & ~(size_t)255;
    return p;
  };
  int*          flags   = (int*)alloc(256);
  int*          gcur    = (int*)alloc(256 * 4);
  unsigned int* stage   = (unsigned int*)alloc((size_t)nbin * CAP * 4);
  int*          csr_src = (int*)alloc((size_t)nbin * CAP * 4);
  int*          row_ptr = (int*)alloc((size_t)N * 4);
  int*          deg     = (int*)alloc((size_t)N * 4);
  float*        dinv    = (float*)alloc((size_t)N * 4);
  ushort_t*     h1      = (ushort_t*)alloc((size_t)N * GCN_HID * 2);  // bf16
  ushort_t*     hag     = (ushort_t*)alloc((size_t)N * GCN_HID * 2);  // bf16
  ushort_t*     wt1     = (ushort_t*)alloc((size_t)GCN_HID * GCN_IN * 2);
  ushort_t*     wt2     = (ushort_t*)alloc((size_t)GCN_OUT * GCN_HID * 2);
  ushort_t*     h2      = h1;  // h1 dead after hag; reuse for GEMM2 output

  // prep_w first: publishes flags[0], zeroes gcur (every graph replay).
  prep_w_kernel<<<(GCN_IN * GCN_HID + GCN_HID * GCN_OUT + 255) / 256, 256, 0, stream>>>(
      W1, W2, wt1, wt2, flags, gcur);

  stageX_kernel<<<nsb, 256, 0, stream>>>(ei, E, gcur, nbin, stage);
  scatter_kernel<<<nbin, 256, 0, stream>>>(stage, gcur, nbin, csr_src,
                                           row_ptr, deg, dinv, N);

  // GEMM1: [N,256] @ [256,128] -> h1 bf16 (MFMA)
  gemm_mfma_kernel<GCN_IN, GCN_HID, 0>
      <<<(N + 31) / 32, 256, 0, stream>>>(x, wt1, h1, N, flags);

  aggregate_relu_kernel<<<(N + 15) / 16, 256, 0, stream>>>(
      h1, row_ptr, deg, csr_src, dinv, b1, hag, N, flags);

  // GEMM2: [N,128] @ [128,64] -> h2 bf16 (MFMA, A bf16)
  gemm_mfma_kernel<GCN_HID, GCN_OUT, 2>
      <<<(N + 31) / 32, 256, 0, stream>>>(hag, wt2, h2, N, flags);

  aggregate_out_kernel<<<(N + 31) / 32, 256, 0, stream>>>(
      h2, row_ptr, deg, csr_src, dinv, b2, d_out, N, flags);
}

// Round 6
// 149.006 us; speedup vs baseline: 1.1535x; 1.0639x over previous
//
#include <hip/hip_runtime.h>

// GCNEncoder: h1 = x@W1; hag = relu(A_norm h1 + b1); h2 = hag@W2; out = A_norm h2 + b2
// A_norm (self loops): out[v] = dinv[v]^2 h[v] + sum_{e:dst=v} dinv[src]dinv[v] h[src]
// Established: float inputs f32 (probed), edges int64 (probed), output f32.
// h1/h2 bf16. GEMMs = MFMA 16x16x32 (128-K-chunk swizzled LDS).
// R20: dispatch restructuring on the proven 158.5us R19 pipeline.
// (1) scatter || GEMM1 in ONE kernel (independent work; 235 latency-bound
//     scatter blocks hide under 938 GEMM1 blocks; 40KB LDS union).
// (2) GEMM2 fused into agg1 epilogue: block's 16 nodes x 128ch hag kept in
//     LDS (XOR-swizzled), W2t staged, 4 MFMA/wave -> h2 direct. hag global
//     round-trip eliminated.
// (3) prep_w folded into stageX (strided); gcur zeroed by 1KB hipMemsetAsync.
// 5 dispatches (memset + 4 kernels), launch overhead ~2.4us each (measured).

#define GCN_IN 256
#define GCN_HID 128
#define GCN_OUT 64

#define BKT 128          // nodes per bucket (dst >> 7)
#define SBE 4096         // edges per superblock
#define CAP 4096         // padded slots per bucket (expected 2560, ~30 sigma)
#define SRCM 0x1FFFFFFu  // 25-bit src mask

typedef unsigned short ushort_t;
typedef __attribute__((ext_vector_type(8))) short short8;     // 8 bf16 (4 VGPR)
typedef __attribute__((ext_vector_type(8))) unsigned short ushort8;
typedef __attribute__((ext_vector_type(4))) float f32x4;

__device__ inline float bf2f(ushort_t u) {
  union { unsigned int i; float f; } x; x.i = ((unsigned int)u) << 16; return x.f;
}
__device__ inline ushort_t f2bf(float f) {
  union { float f; unsigned int i; } u; u.f = f;
  unsigned int r = u.i + 0x7FFFu + ((u.i >> 16) & 1u);  // RNE
  return (ushort_t)(r >> 16);
}

// ---- stageX (+W prep +flags): fused hist + reserve + bucket-scatter ----
// Per superblock: cache 16 edges/thread in registers, LDS hist over 235
// buckets, one global atomicAdd per non-empty bucket to reserve a window in
// the padded stage array, LDS-cursor scatter. W transpose+bf16 strided across
// blocks; block 0 publishes flags[0]. gcur pre-zeroed by hipMemsetAsync.
__global__ __launch_bounds__(256)
void stageX_kernel(const int* __restrict__ ei, int E,
                   const void* __restrict__ W1, const void* __restrict__ W2,
                   ushort_t* __restrict__ Wt1, ushort_t* __restrict__ Wt2,
                   int* __restrict__ flags,
                   int* __restrict__ gcur, int nbin,
                   unsigned int* __restrict__ stage) {
  __shared__ int lcnt[256];
  __shared__ int cur[256];
  __shared__ int nzc, csh;
  const int t = threadIdx.x;
  const int sb = blockIdx.x;
  lcnt[t] = 0;
  if (t == 0) { nzc = 0; csh = 0; }
  __syncthreads();
  if (t < 128) {
    if (ei[2 * t + 1] != 0) atomicAdd(&nzc, 1);     // i64 high words all zero
    ushort_t u = ((const ushort_t*)W1)[2 * t];
    int e = (u >> 7) & 0xFF;
    if (e >= 100 && e <= 140) atomicAdd(&csh, 1);   // bf16-looking exponents
  }
  __syncthreads();
  const bool i64 = (nzc == 0);
  const bool f32 = (csh < 64);
  if (sb == 0 && t == 0) flags[0] = f32 ? 1 : 0;    // read by later dispatches

  // W prep (40960 elems over gridDim blocks)
  for (int i = sb * 256 + t; i < GCN_IN * GCN_HID + GCN_HID * GCN_OUT;
       i += gridDim.x * 256) {
    if (i < GCN_IN * GCN_HID) {                     // W1[k][n] -> Wt1[n][k]
      int k = i >> 7, nn = i & 127;
      float vv = f32 ? ((const float*)W1)[i] : bf2f(((const ushort_t*)W1)[i]);
      Wt1[nn * GCN_IN + k] = f2bf(vv);
    } else {                                        // W2[k][n] -> Wt2[n][k]
      int j = i - GCN_IN * GCN_HID;
      int k = j >> 6, nn = j & 63;
      float vv = f32 ? ((const float*)W2)[j] : bf2f(((const ushort_t*)W2)[j]);
      Wt2[nn * GCN_HID + k] = f2bf(vv);
    }
  }

  const int base = sb * SBE;
  int end = base + SBE; if (end > E) end = E;
  unsigned int p[16];
  int bk[16];
#pragma unroll
  for (int k = 0; k < 16; ++k) {
    int i = base + t + k * 256;
    bk[k] = -1;
    if (i < end) {
      int s, d;
      if (i64) { s = ei[2 * i]; d = ei[2 * E + 2 * i]; }
      else     { s = ei[i];     d = ei[E + i]; }
      p[k] = (unsigned int)s | ((unsigned int)(d & 127) << 25);
      bk[k] = d >> 7;
      atomicAdd(&lcnt[bk[k]], 1);             // LDS atomic
    }
  }
  __syncthreads();
  for (int b = t; b < nbin; b += 256) {
    int c = lcnt[b];
    cur[b] = b * CAP + (c ? atomicAdd(&gcur[b], c) : 0);  // global reservation
  }
  __syncthreads();
#pragma unroll
  for (int k = 0; k < 16; ++k) {
    if (bk[k] >= 0) {
      int pos = atomicAdd(&cur[bk[k]], 1);    // LDS atomic cursor
      if (pos < (bk[k] + 1) * CAP)            // overflow guard (never expected)
        stage[pos] = p[k];
    }
  }
}

// ---- scatter body: block per bucket (device function; LDS passed in) ----
__device__ void scatter_body(char* lds,
                             const unsigned int* __restrict__ stage,
                             const int* __restrict__ gcur, int nbin,
                             int* __restrict__ csr_src,
                             int* __restrict__ row_ptr, int* __restrict__ deg,
                             float* __restrict__ dinv, int n, int b) {
  int* lcnt  = (int*)lds;
  int* lscan = lcnt + BKT;
  int* lcur  = lcnt + 2 * BKT;
  const int t = threadIdx.x;                // 256 threads
  const int node0 = b * BKT;
  const int nn = (n - node0 < BKT) ? (n - node0) : BKT;
  const int rb = b * CAP;
  const int re = rb + gcur[b];
  if (t < BKT) lcnt[t] = 0;
  __syncthreads();
  for (int i = rb + t; i < re; i += 256)
    atomicAdd(&lcnt[stage[i] >> 25], 1);    // LDS atomic, 128 counters
  __syncthreads();
  if (t < BKT) lscan[t] = lcnt[t];
  __syncthreads();
  for (int off = 1; off < BKT; off <<= 1) {  // Hillis-Steele inclusive scan
    int v = 0;
    if (t < BKT && t >= off) v = lscan[t - off];
    __syncthreads();
    if (t < BKT) lscan[t] += v;
    __syncthreads();
  }
  if (t < BKT) {
    int excl = rb + lscan[t] - lcnt[t];
    lcur[t] = excl;
    if (t < nn) {
      row_ptr[node0 + t] = excl;
      deg[node0 + t] = lcnt[t];
      dinv[node0 + t] = rsqrtf((float)(lcnt[t] + 1));  // +1 self loop
    }
  }
  __syncthreads();
  for (int i = rb + t; i < re; i += 256) {
    unsigned int p = stage[i];
    int l = p >> 25;
    int pos = atomicAdd(&lcur[l], 1);       // LDS atomic cursor
    csr_src[pos] = (int)(p & SRCM);         // write within ~10KB window
  }
}

// ---- GEMM1 body: C[M,128] = A[M,256] @ Bt[128,256]^T (device function) ----
// Full 128-K-chunk staged in LDS (A 8KB + B 32KB), XOR-swizzle
// byte ^= (row&7)<<4 kills the stride-256B bank conflict.
__device__ void gemm1_body(char* lds, const void* __restrict__ A,
                           const ushort_t* __restrict__ Bt,
                           ushort_t* __restrict__ C, int M,
                           const int* __restrict__ flags, int bid) {
  constexpr int K = GCN_IN, NC = GCN_HID;
  constexpr int KH = 128;
  constexpr int KPC = KH / 8;                 // 16B chunks per row
  constexpr int NT = NC / 32;
  ushort_t* As = (ushort_t*)lds;              // 32*128 = 8KB
  ushort_t* Bs = As + 32 * KH;                // 128*128 = 32KB
  const int tid = threadIdx.x;
  const int wv = tid >> 6;
  const int lane = tid & 63;
  const int ml = lane & 15;
  const int quad = lane >> 4;
  const int row0 = bid * 32;
  const int mrow = (wv & 1) * 16 + ml;
  const int ncol0 = (wv >> 1) * (NC / 2);
  const bool aF32 = (flags[0] != 0);
  f32x4 acc[NT] = {};

  for (int ch = 0; ch < K; ch += KH) {
    if (ch) __syncthreads();                  // all waves done with prev chunk
    for (int c = tid; c < 32 * KPC; c += 256) {
      int r = c / KPC, cq = c % KPC;
      ushort8 o;
      if (row0 + r < M) {
        if (aF32) {
          const float* ap = (const float*)A + (size_t)(row0 + r) * K + ch + cq * 8;
          float4 f0 = *(const float4*)ap;
          float4 f1 = *(const float4*)(ap + 4);
          o[0] = f2bf(f0.x); o[1] = f2bf(f0.y); o[2] = f2bf(f0.z); o[3] = f2bf(f0.w);
          o[4] = f2bf(f1.x); o[5] = f2bf(f1.y); o[6] = f2bf(f1.z); o[7] = f2bf(f1.w);
        } else {
          o = *(const ushort8*)((const ushort_t*)A + (size_t)(row0 + r) * K + ch + cq * 8);
        }
      } else {
        o = (ushort8)0;
      }
      int byte = (cq * 16) ^ ((r & 7) << 4);
      *(ushort8*)((char*)As + r * (KH * 2) + byte) = o;
    }
    for (int c = tid; c < NC * KPC; c += 256) {
      int nr = c / KPC, cq = c % KPC;
      ushort8 o = *(const ushort8*)(Bt + (size_t)nr * K + ch + cq * 8);
      int byte = (cq * 16) ^ ((nr & 7) << 4);
      *(ushort8*)((char*)Bs + nr * (KH * 2) + byte) = o;
    }
    __syncthreads();
#pragma unroll
    for (int kt = 0; kt < KH; kt += 32) {
      int abyte = (kt * 2 + quad * 16) ^ ((mrow & 7) << 4);
      short8 af = *(const short8*)((const char*)As + mrow * (KH * 2) + abyte);
#pragma unroll
      for (int t = 0; t < NT; ++t) {
        int nr = ncol0 + t * 16 + ml;
        int bbyte = (kt * 2 + quad * 16) ^ ((nr & 7) << 4);
        short8 bf = *(const short8*)((const char*)Bs + nr * (KH * 2) + bbyte);
        acc[t] = __builtin_amdgcn_mfma_f32_16x16x32_bf16(af, bf, acc[t], 0, 0, 0);
      }
    }
  }

  const int orow = row0 + (wv & 1) * 16 + quad * 4;
#pragma unroll
  for (int t = 0; t < NT; ++t) {
    int col = ncol0 + t * 16 + ml;
#pragma unroll
    for (int r = 0; r < 4; ++r) {
      if (orow + r < M)
        C[(size_t)(orow + r) * NC + col] = f2bf(acc[t][r]);
    }
  }
}

// ---- fused dispatch: blocks [0,nbin) scatter; blocks [nbin,..) GEMM1 ----
__global__ __launch_bounds__(256)
void scatter_gemm1_kernel(const unsigned int* __restrict__ stage,
                          const int* __restrict__ gcur, int nbin,
                          int* __restrict__ csr_src,
                          int* __restrict__ row_ptr, int* __restrict__ deg,
                          float* __restrict__ dinv, int n,
                          const void* __restrict__ x,
                          const ushort_t* __restrict__ wt1,
                          ushort_t* __restrict__ h1,
                          const int* __restrict__ flags) {
  __shared__ __align__(16) char lds[32 * 128 * 2 + 128 * 128 * 2];  // 40KB union
  const int b = blockIdx.x;
  if (b < nbin) {
    scatter_body(lds, stage, gcur, nbin, csr_src, row_ptr, deg, dinv, n, b);
  } else {
    gemm1_body(lds, x, wt1, h1, n, flags, b - nbin);
  }
}

// ---- agg1 + GEMM2 fused: 16-lane group per node; hag kept in LDS ----
// Phase A (agg): group = 16 lanes = 1 node (16 nodes/block). Lane q owns
// channels q*8..q*8+7; 4-deep in-group unroll keeps 4 gathers in flight; oob
// lanes carry sv=0,dv=0 (zero-weight h[0] gather). relu+bias epilogue writes
// the node's hag row into swizzled LDS (never to global).
// Phase B (GEMM2): stage W2t[64][128] swizzled (prefetched before phase A's
// edge loop); 4 waves x 4 MFMA: wave w computes cols w*16..+15 of
// h2[16 nodes][64] = hagS @ W2t^T.
__global__ __launch_bounds__(256)
void agg1_gemm2_kernel(const ushort_t* __restrict__ h,
                       const int* __restrict__ row_ptr,
                       const int* __restrict__ deg,
                       const int* __restrict__ csr_src,
                       const float* __restrict__ dinv,
                       const void* __restrict__ bias,
                       const ushort_t* __restrict__ wt2,
                       ushort_t* __restrict__ h2, int n,
                       const int* __restrict__ flags) {
  __shared__ __align__(16) ushort_t hagS[16 * GCN_HID];   // 4KB, swizzled
  __shared__ __align__(16) ushort_t w2S[GCN_OUT * GCN_HID]; // 16KB, swizzled
  const int tid = threadIdx.x;
  const int lane = tid & 63;
  const int ni = tid >> 4;                             // node index in block
  const int v0 = blockIdx.x * 16;
  const int v = v0 + ni;
  const int q = lane & 15;
  const int gb = lane & 48;                            // group base in wave

  // stage W2t (64 rows x 128 cols bf16), swizzled; no dependency on agg
  for (int c = tid; c < GCN_OUT * (GCN_HID / 8); c += 256) {
    int nr = c >> 4, cq = c & 15;
    ushort8 o = *(const ushort8*)(wt2 + (size_t)nr * GCN_HID + cq * 8);
    int byte = (cq * 16) ^ ((nr & 7) << 4);
    *(ushort8*)((char*)w2S + nr * (GCN_HID * 2) + byte) = o;
  }

  if (v < n) {
    float acc[8] = {};
    const int beg = row_ptr[v];
    const int end = beg + deg[v];
    for (int base = beg; base < end; base += 16) {
      int navail = end - base; if (navail > 16) navail = 16;
      int sv = 0; float dv = 0.f;
      if (base + q < end) { sv = csr_src[base + q]; dv = dinv[sv]; }
      for (int j = 0; j < navail; j += 4) {
        int s0 = __shfl(sv, gb + j + 0), s1 = __shfl(sv, gb + j + 1);
        int s2 = __shfl(sv, gb + j + 2), s3 = __shfl(sv, gb + j + 3);
        float d0 = __shfl(dv, gb + j + 0), d1 = __shfl(dv, gb + j + 1);
        float d2 = __shfl(dv, gb + j + 2), d3 = __shfl(dv, gb + j + 3);
        ushort8 hv0 = *(const ushort8*)(h + (size_t)s0 * GCN_HID + q * 8);
        ushort8 hv1 = *(const ushort8*)(h + (size_t)s1 * GCN_HID + q * 8);
        ushort8 hv2 = *(const ushort8*)(h + (size_t)s2 * GCN_HID + q * 8);
        ushort8 hv3 = *(const ushort8*)(h + (size_t)s3 * GCN_HID + q * 8);
#pragma unroll
        for (int k = 0; k < 8; ++k) {
          acc[k] = fmaf(d0, bf2f(hv0[k]), acc[k]);
          acc[k] = fmaf(d1, bf2f(hv1[k]), acc[k]);
          acc[k] = fmaf(d2, bf2f(hv2[k]), acc[k]);
          acc[k] = fmaf(d3, bf2f(hv3[k]), acc[k]);
        }
      }
    }
    float di = dinv[v];
    float sl = di * di;
    ushort8 hv = *(const ushort8*)(h + (size_t)v * GCN_HID + q * 8);
    const bool bF32 = flags[0] != 0;
    ushort8 o;
#pragma unroll
    for (int k = 0; k < 8; ++k) {
      float bv = bF32 ? ((const float*)bias)[q * 8 + k]
                      : bf2f(((const ushort_t*)bias)[q * 8 + k]);
      o[k] = f2bf(fmaxf(di * acc[k] + sl * bf2f(hv[k]) + bv, 0.f));
    }
    int byte = (q * 16) ^ ((ni & 7) << 4);
    *(ushort8*)((char*)hagS + ni * (GCN_HID * 2) + byte) = o;  // swizzled LDS
  }
  __syncthreads();

  // GEMM2: h2[16][64] = hagS[16][128] @ w2S[64][128]^T
  const int wv = tid >> 6;
  const int ml = lane & 15;
  const int quad = lane >> 4;
  f32x4 acc2 = {};
#pragma unroll
  for (int kt = 0; kt < GCN_HID; kt += 32) {
    int abyte = (kt * 2 + quad * 16) ^ ((ml & 7) << 4);
    short8 af = *(const short8*)((const char*)hagS + ml * (GCN_HID * 2) + abyte);
    int nr = wv * 16 + ml;
    int bbyte = (kt * 2 + quad * 16) ^ ((nr & 7) << 4);
    short8 bf = *(const short8*)((const char*)w2S + nr * (GCN_HID * 2) + bbyte);
    acc2 = __builtin_amdgcn_mfma_f32_16x16x32_bf16(af, bf, acc2, 0, 0, 0);
  }
  const int col = wv * 16 + ml;
#pragma unroll
  for (int r = 0; r < 4; ++r) {
    int row = quad * 4 + r;                 // node row in 0..15
    if (v0 + row < n)
      h2[(size_t)(v0 + row) * GCN_OUT + col] = f2bf(acc2[r]);
  }
}

// agg2: group = 8 lanes = 1 node (8 nodes/wave), 128B rows, same scheme.
__global__ void aggregate_out_kernel(const ushort_t* __restrict__ h,
                                     const int* __restrict__ row_ptr,
                                     const int* __restrict__ deg,
                                     const int* __restrict__ csr_src,
                                     const float* __restrict__ dinv,
                                     const void* __restrict__ bias,
                                     void* __restrict__ outp, int n,
                                     const int* __restrict__ flags) {
  const int lane = threadIdx.x & 63;
  const int v = blockIdx.x * 32 + (threadIdx.x >> 3);  // 32 nodes per block
  if (v >= n) return;
  const int q = lane & 7;
  const int gb = lane & 56;                            // group base in wave
  float acc[8] = {};
  const int beg = row_ptr[v];
  const int end = beg + deg[v];
  for (int base = beg; base < end; base += 8) {
    int navail = end - base; if (navail > 8) navail = 8;
    int sv = 0; float dv = 0.f;
    if (base + q < end) { sv = csr_src[base + q]; dv = dinv[sv]; }
    for (int j = 0; j < navail; j += 4) {
      int s0 = __shfl(sv, gb + j + 0), s1 = __shfl(sv, gb + j + 1);
      int s2 = __shfl(sv, gb + j + 2), s3 = __shfl(sv, gb + j + 3);
      float d0 = __shfl(dv, gb + j + 0), d1 = __shfl(dv, gb + j + 1);
      float d2 = __shfl(dv, gb + j + 2), d3 = __shfl(dv, gb + j + 3);
      ushort8 hv0 = *(const ushort8*)(h + (size_t)s0 * GCN_OUT + q * 8);
      ushort8 hv1 = *(const ushort8*)(h + (size_t)s1 * GCN_OUT + q * 8);
      ushort8 hv2 = *(const ushort8*)(h + (size_t)s2 * GCN_OUT + q * 8);
      ushort8 hv3 = *(const ushort8*)(h + (size_t)s3 * GCN_OUT + q * 8);
#pragma unroll
      for (int k = 0; k < 8; ++k) {
        acc[k] = fmaf(d0, bf2f(hv0[k]), acc[k]);
        acc[k] = fmaf(d1, bf2f(hv1[k]), acc[k]);
        acc[k] = fmaf(d2, bf2f(hv2[k]), acc[k]);
        acc[k] = fmaf(d3, bf2f(hv3[k]), acc[k]);
      }
    }
  }
  float di = dinv[v];
  float sl = di * di;
  ushort8 hv = *(const ushort8*)(h + (size_t)v * GCN_OUT + q * 8);
  const bool oF32 = flags[0] != 0;
  float r[8];
#pragma unroll
  for (int k = 0; k < 8; ++k) {
    float bv = oF32 ? ((const float*)bias)[q * 8 + k]
                    : bf2f(((const ushort_t*)bias)[q * 8 + k]);
    r[k] = di * acc[k] + sl * bf2f(hv[k]) + bv;
  }
  if (oF32) {
    float* op = (float*)outp + (size_t)v * GCN_OUT + q * 8;
    *(float4*)op = make_float4(r[0], r[1], r[2], r[3]);
    *(float4*)(op + 4) = make_float4(r[4], r[5], r[6], r[7]);
  } else {
    ushort8 o;
#pragma unroll
    for (int k = 0; k < 8; ++k) o[k] = f2bf(r[k]);
    *(ushort8*)((ushort_t*)outp + (size_t)v * GCN_OUT + q * 8) = o;
  }
}

// ---------------- launch ----------------

extern "C" void kernel_launch(void* const* d_in, const int* in_sizes, int n_in,
                              void* d_out, int out_size, void* d_ws, size_t ws_size,
                              hipStream_t stream) {
  const void* x  = d_in[0];               // [N, 256] f32 (probed)
  const int*  ei = (const int*)d_in[1];   // [2, E] int32/int64 (probed)
  const void* W1 = d_in[2];               // [256,128]
  const void* b1 = d_in[3];               // [128]
  const void* W2 = d_in[4];               // [128,64]
  const void* b2 = d_in[5];               // [64]

  const int N = in_sizes[0] / GCN_IN;     // 30000
  const int E = in_sizes[1] / 2;          // 600000
  const int nsb  = (E + SBE - 1) / SBE;   // 147 superblocks
  const int nbin = (N + BKT - 1) / BKT;   // 235 buckets (<=256)

  size_t off = 0;
  auto alloc = [&](size_t bytes) -> void* {
    void* p = (char*)d_ws + off;
    off += (bytes + 255) & ~(size_t)255;
    return p;
  };
  int*          flags   = (int*)alloc(256);
  int*          gcur    = (int*)alloc(256 * 4);
  unsigned int* stage   = (unsigned int*)alloc((size_t)nbin * CAP * 4);
  int*          csr_src = (int*)alloc((size_t)nbin * CAP * 4);
  int*          row_ptr = (int*)alloc((size_t)N * 4);
  int*          deg     = (int*)alloc((size_t)N * 4);
  float*        dinv    = (float*)alloc((size_t)N * 4);
  ushort_t*     h1      = (ushort_t*)alloc((size_t)N * GCN_HID * 2);  // bf16
  ushort_t*     h2      = (ushort_t*)alloc((size_t)N * GCN_OUT * 2);  // bf16
  ushort_t*     wt1     = (ushort_t*)alloc((size_t)GCN_HID * GCN_IN * 2);
  ushort_t*     wt2     = (ushort_t*)alloc((size_t)GCN_OUT * GCN_HID * 2);

  hipMemsetAsync(gcur, 0, 256 * 4, stream);

  stageX_kernel<<<nsb, 256, 0, stream>>>(ei, E, W1, W2, wt1, wt2, flags,
                                         gcur, nbin, stage);

  // scatter (235 blocks) || GEMM1 (938 blocks) in one dispatch
  const int nGemm1 = (N + 31) / 32;
  scatter_gemm1_kernel<<<nbin + nGemm1, 256, 0, stream>>>(
      stage, gcur, nbin, csr_src, row_ptr, deg, dinv, N, x, wt1, h1, flags);

  // agg1 + GEMM2 fused: hag in LDS, h2 = relu(A h1 + b1) @ W2
  agg1_gemm2_kernel<<<(N + 15) / 16, 256, 0, stream>>>(
      h1, row_ptr, deg, csr_src, dinv, b1, wt2, h2, N, flags);

  aggregate_out_kernel<<<(N + 31) / 32, 256, 0, stream>>>(
      h2, row_ptr, deg, csr_src, dinv, b2, d_out, N, flags);
}